// Round 5
// baseline (31758.740 us; speedup 1.0000x reference)
//
#include <hip/hip_runtime.h>
#include <hip/hip_bf16.h>
#include <stdint.h>

#define BQ 16      // batch
#define TT 4096    // timesteps
#define II 128     // input features
#define HH 256     // hidden
#define RING 256   // h-ring slots (power of 2)

typedef __attribute__((ext_vector_type(8))) short bf16x8;  // 8 bf16 (4 VGPRs)
typedef __attribute__((ext_vector_type(4))) float f32x4;   // MFMA acc
typedef unsigned short ushort_t;

__device__ __forceinline__ float sigmoidf_(float x) { return 1.0f / (1.0f + __expf(-x)); }

__device__ __forceinline__ ushort_t bf16r(float x) {
    __hip_bfloat16 h = __float2bfloat16(x);       // RTN
    union { __hip_bfloat16 h; ushort_t u; } c; c.h = h; return c.u;
}
__device__ __forceinline__ float f32up(ushort_t u) {
    union { unsigned int i; float f; } c; c.i = ((unsigned int)u) << 16; return c.f;
}

__device__ __forceinline__ void poll_ge(const int* p, int target) {
    while (__hip_atomic_load(p, __ATOMIC_ACQUIRE, __HIP_MEMORY_SCOPE_AGENT) < target)
        __builtin_amdgcn_s_sleep(2);
}

__device__ __forceinline__ f32x4 MF(bf16x8 a, bf16x8 b, f32x4 c) {
    return __builtin_amdgcn_mfma_f32_16x16x32_bf16(a, b, c, 0, 0, 0);
}

// Build one B-fragment (hi/lo split) from 8 consecutive fp32 weights.
__device__ __forceinline__ void load_wfrag(const float* p, bf16x8* hi, bf16x8* lo) {
    float4 a = *(const float4*)p;
    float4 b = *(const float4*)(p + 4);
    float vv[8] = {a.x, a.y, a.z, a.w, b.x, b.y, b.z, b.w};
#pragma unroll
    for (int j = 0; j < 8; j++) {
        ushort_t h = bf16r(vv[j]);
        (*hi)[j] = (short)h;
        (*lo)[j] = (short)bf16r(vv[j] - f32up(h));
    }
}

// x -> bf16 hi/lo split, elementwise (once per launch)
__global__ __launch_bounds__(256)
void prep_x(const float* __restrict__ xx, ushort_t* __restrict__ xh,
            ushort_t* __restrict__ xl, int n4) {
    int i = blockIdx.x * 256 + threadIdx.x;
    const int stride = gridDim.x * 256;
    for (; i < n4; i += stride) {
        const float4 v = ((const float4*)xx)[i];
        float a[4] = {v.x, v.y, v.z, v.w};
        ushort_t h[4], l[4];
#pragma unroll
        for (int j = 0; j < 4; j++) { h[j] = bf16r(a[j]); l[j] = bf16r(a[j] - f32up(h[j])); }
        ushort4 hv = {h[0], h[1], h[2], h[3]};
        ushort4 lv = {l[0], l[1], l[2], l[3]};
        ((ushort4*)xh)[i] = hv;
        ((ushort4*)xl)[i] = lv;
    }
}

// Fused 2-layer LSTM scan via MFMA, batch(16) = M dim.
// Grid: 24 WGs x 512 thr.
//  bid 0..7  = L0 WG w: owns h1[j = w*32 .. +32). waves v: q=v>>1, half=v&1,
//              N-tile n0 = q*256 + w*32 + half*16. K = 256(h1_{t-1}) + 128(x_t),
//              weights (Whh0,Wih0 rows, bf16 hi/lo) in VGPR fragments.
//  bid 8..23 = L1 WG w2: owns h2[j = w2*16 .. +16). waves v: q=v&3, kh=v>>2,
//              kh=0: Whh1 over h2_{t-1} (+b1 init), kh=1: Wih1 over h1_t.
//              Partial sums joined via LDS.
// Split-bf16: 3 MFMAs per (A,B) tile: Ah*Bh + Al*Bh + Ah*Bl (~fp32 accuracy).
// Handshake: cnt0[t] (8 L0 WGs), cnt1[t] (16 L1 WGs); acquire-poll / release-add.
// h rings (bf16 hi/lo, [RING][16][256]); L0 backpressure: cnt1[t-RING] done.
__global__ __launch_bounds__(512, 1)
void lstm_mfma(const float* __restrict__ Wih0, const float* __restrict__ Whh0,
               const float* __restrict__ b0v,
               const float* __restrict__ Wih1, const float* __restrict__ Whh1,
               const float* __restrict__ b1v,
               const ushort_t* __restrict__ xh, const ushort_t* __restrict__ xl,
               ushort_t* h1h, ushort_t* h1l, ushort_t* h2h, ushort_t* h2l,
               float* out, int* cnt0, int* cnt1)
{
    const int tid = threadIdx.x;
    const int lane = tid & 63;
    const int v = tid >> 6;        // wave 0..7
    const int ln15 = lane & 15;    // M (batch) / N (gate-col) index within tile
    const int kgrp = lane >> 4;    // 0..3
    const int bid = blockIdx.x;

    __shared__ float gates0[4][16][32];   // L0: [gate][batch][j-local]
    __shared__ float part1[4][16][16];    // L1: kh=1 partials
    __shared__ float gates1[4][16][16];   // L1

    if (bid < 8) {
        // ----------------------------- layer 0 -----------------------------
        const int w = bid;
        const int q = v >> 1, half = v & 1;
        const int n0 = q * 256 + w * 32 + half * 16;
        const int nrow = n0 + ln15;

        bf16x8 whh[8], whl[8];     // Whh0 fragments (K=256)
#pragma unroll
        for (int ks = 0; ks < 8; ks++)
            load_wfrag(Whh0 + (size_t)nrow * HH + ks * 32 + kgrp * 8, &whh[ks], &whl[ks]);
        bf16x8 wxh[4], wxl[4];     // Wih0 fragments (K=128)
#pragma unroll
        for (int ks = 0; ks < 4; ks++)
            load_wfrag(Wih0 + (size_t)nrow * II + ks * 32 + kgrp * 8, &wxh[ks], &wxl[ks]);
        const float bias = b0v[nrow];

        float c_reg = 0.f;  // c-update: thread (b=tid>>5, jl=tid&31)

        for (int t = 0; t < TT; t++) {
            const int slot = t & (RING - 1);
            const int pslot = (t - 1) & (RING - 1);
            f32x4 acc = {bias, bias, bias, bias};

            // x contribution first (independent of the recurrence)
#pragma unroll
            for (int ks = 0; ks < 4; ks++) {
                const size_t ao = ((size_t)ln15 * TT + t) * II + ks * 32 + kgrp * 8;
                bf16x8 ah = *(const bf16x8*)(xh + ao);
                bf16x8 al = *(const bf16x8*)(xl + ao);
                acc = MF(ah, wxh[ks], acc);
                acc = MF(al, wxh[ks], acc);
                acc = MF(ah, wxl[ks], acc);
            }
            if (t >= RING) poll_ge(cnt1 + (t - RING), 16);  // ring backpressure
            if (t > 0) {
                poll_ge(cnt0 + t - 1, 8);
#pragma unroll
                for (int ks = 0; ks < 8; ks++) {
                    const size_t ao = ((size_t)pslot * BQ + ln15) * HH + ks * 32 + kgrp * 8;
                    bf16x8 ah = *(const bf16x8*)(h1h + ao);
                    bf16x8 al = *(const bf16x8*)(h1l + ao);
                    acc = MF(ah, whh[ks], acc);
                    acc = MF(al, whh[ks], acc);
                    acc = MF(ah, whl[ks], acc);
                }
            }
            // activate; D: row(batch) = kgrp*4+r, col(gate) = n0+ln15
#pragma unroll
            for (int r = 0; r < 4; r++) {
                float a = acc[r];
                a = (q == 2) ? tanhf(a) : sigmoidf_(a);
                gates0[q][kgrp * 4 + r][half * 16 + ln15] = a;
            }
            __syncthreads();
            {
                const int b = tid >> 5, jl = tid & 31;
                const float iv = gates0[0][b][jl];
                const float fv = gates0[1][b][jl];
                const float gv = gates0[2][b][jl];
                const float ov = gates0[3][b][jl];
                c_reg = fmaf(fv, c_reg, iv * gv);
                const float hv = ov * tanhf(c_reg);
                const ushort_t hh = bf16r(hv);
                const ushort_t hl = bf16r(hv - f32up(hh));
                const size_t off = ((size_t)slot * BQ + b) * HH + w * 32 + jl;
                h1h[off] = hh;
                h1l[off] = hl;
            }
            __syncthreads();
            if (tid == 0)
                __hip_atomic_fetch_add(cnt0 + t, 1, __ATOMIC_RELEASE, __HIP_MEMORY_SCOPE_AGENT);
        }
    } else {
        // ----------------------------- layer 1 -----------------------------
        const int w2 = bid - 8;
        const int q = v & 3, kh = v >> 2;
        const int n0 = q * 256 + w2 * 16;
        const int nrow = n0 + ln15;

        bf16x8 wfh[8], wfl[8];
        const float* WW = kh ? Wih1 : Whh1;
#pragma unroll
        for (int ks = 0; ks < 8; ks++)
            load_wfrag(WW + (size_t)nrow * HH + ks * 32 + kgrp * 8, &wfh[ks], &wfl[ks]);
        const float bias = kh ? 0.f : b1v[nrow];

        float c_reg = 0.f;  // c-update: tid<256, (b=tid>>4, jl=tid&15)

        for (int t = 0; t < TT; t++) {
            const int slot = t & (RING - 1);
            const int pslot = (t - 1) & (RING - 1);
            f32x4 acc = {bias, bias, bias, bias};

            if (kh) {
                // h1_t contribution
                poll_ge(cnt0 + t, 8);
#pragma unroll
                for (int ks = 0; ks < 8; ks++) {
                    const size_t ao = ((size_t)slot * BQ + ln15) * HH + ks * 32 + kgrp * 8;
                    bf16x8 ah = *(const bf16x8*)(h1h + ao);
                    bf16x8 al = *(const bf16x8*)(h1l + ao);
                    acc = MF(ah, wfh[ks], acc);
                    acc = MF(al, wfh[ks], acc);
                    acc = MF(ah, wfl[ks], acc);
                }
#pragma unroll
                for (int r = 0; r < 4; r++) part1[q][kgrp * 4 + r][ln15] = acc[r];
            } else if (t > 0) {
                // h2_{t-1} contribution
                poll_ge(cnt1 + t - 1, 16);
#pragma unroll
                for (int ks = 0; ks < 8; ks++) {
                    const size_t ao = ((size_t)pslot * BQ + ln15) * HH + ks * 32 + kgrp * 8;
                    bf16x8 ah = *(const bf16x8*)(h2h + ao);
                    bf16x8 al = *(const bf16x8*)(h2l + ao);
                    acc = MF(ah, wfh[ks], acc);
                    acc = MF(al, wfh[ks], acc);
                    acc = MF(ah, wfl[ks], acc);
                }
            }
            __syncthreads();
            if (!kh) {
#pragma unroll
                for (int r = 0; r < 4; r++) {
                    float a = acc[r] + part1[q][kgrp * 4 + r][ln15];
                    a = (q == 2) ? tanhf(a) : sigmoidf_(a);
                    gates1[q][kgrp * 4 + r][ln15] = a;
                }
            }
            __syncthreads();
            if (tid < 256) {
                const int b = tid >> 4, jl = tid & 15;
                const float iv = gates1[0][b][jl];
                const float fv = gates1[1][b][jl];
                const float gv = gates1[2][b][jl];
                const float ov = gates1[3][b][jl];
                c_reg = fmaf(fv, c_reg, iv * gv);
                const float hv = ov * tanhf(c_reg);
                out[((size_t)b * TT + t) * HH + w2 * 16 + jl] = hv;
                const ushort_t hh = bf16r(hv);
                const ushort_t hl = bf16r(hv - f32up(hh));
                const size_t off = ((size_t)slot * BQ + b) * HH + w2 * 16 + jl;
                h2h[off] = hh;
                h2l[off] = hl;
            }
            __syncthreads();
            if (tid == 0)
                __hip_atomic_fetch_add(cnt1 + t, 1, __ATOMIC_RELEASE, __HIP_MEMORY_SCOPE_AGENT);
        }
    }
}

extern "C" void kernel_launch(void* const* d_in, const int* in_sizes, int n_in,
                              void* d_out, int out_size, void* d_ws, size_t ws_size,
                              hipStream_t stream) {
    (void)in_sizes; (void)n_in; (void)out_size; (void)ws_size;
    const float* x    = (const float*)d_in[0];
    const float* Wih0 = (const float*)d_in[1];
    const float* Whh0 = (const float*)d_in[2];
    const float* b0   = (const float*)d_in[3];
    const float* Wih1 = (const float*)d_in[4];
    const float* Whh1 = (const float*)d_in[5];
    const float* b1   = (const float*)d_in[6];
    float* out = (float*)d_out;

    // ---- workspace carve (~42 MB) ----
    char* ws = (char*)d_ws;
    int* cnt0 = (int*)ws;                               // [TT]
    int* cnt1 = cnt0 + TT;                              // [TT]
    ushort_t* xh  = (ushort_t*)(cnt1 + TT);             // [BQ][TT][II]
    ushort_t* xl  = xh + (size_t)BQ * TT * II;
    ushort_t* h1h = xl + (size_t)BQ * TT * II;          // [RING][BQ][HH]
    ushort_t* h1l = h1h + (size_t)RING * BQ * HH;
    ushort_t* h2h = h1l + (size_t)RING * BQ * HH;
    ushort_t* h2l = h2h + (size_t)RING * BQ * HH;

    hipMemsetAsync(cnt0, 0, 2 * TT * sizeof(int), stream);
    prep_x<<<2048, 256, 0, stream>>>(x, xh, xl, BQ * TT * II / 4);
    lstm_mfma<<<24, 512, 0, stream>>>(Wih0, Whh0, b0, Wih1, Whh1, b1,
                                      xh, xl, h1h, h1l, h2h, h2l,
                                      out, cnt0, cnt1);
}

// Round 6
// 31272.269 us; speedup vs baseline: 1.0156x; 1.0156x over previous
//
#include <hip/hip_runtime.h>
#include <hip/hip_bf16.h>
#include <stdint.h>

#define BQ 16      // batch
#define TT 4096    // timesteps
#define II 128     // input features
#define HH 256     // hidden
#define RING 256   // h-ring slots (power of 2)

typedef __attribute__((ext_vector_type(8))) short bf16x8;  // 8 bf16 (4 VGPRs/AGPRs)
typedef __attribute__((ext_vector_type(4))) float f32x4;   // MFMA acc
typedef unsigned short ushort_t;

__device__ __forceinline__ float sigmoidf_(float x) { return 1.0f / (1.0f + __expf(-x)); }

__device__ __forceinline__ ushort_t bf16r(float x) {
    __hip_bfloat16 h = __float2bfloat16(x);       // RTN
    union { __hip_bfloat16 h; ushort_t u; } c; c.h = h; return c.u;
}
__device__ __forceinline__ float f32up(ushort_t u) {
    union { unsigned int i; float f; } c; c.i = ((unsigned int)u) << 16; return c.f;
}

__device__ __forceinline__ void poll_ge(const int* p, int target) {
    while (__hip_atomic_load(p, __ATOMIC_ACQUIRE, __HIP_MEMORY_SCOPE_AGENT) < target)
        __builtin_amdgcn_s_sleep(2);
}

// MFMA with B pinned in AGPR (gfx950: A,B may source from AGPR).
#define MFA(ACC, A, B)                                                          \
    asm volatile("v_mfma_f32_16x16x32_bf16 %0, %1, %2, %0"                      \
                 : "+v"(ACC) : "v"(A), "a"(B))

struct WPair { bf16x8 h, l; };
__device__ __forceinline__ WPair wsplit(const float* p) {
    float4 a = *(const float4*)p;
    float4 b = *(const float4*)(p + 4);
    float vv[8] = {a.x, a.y, a.z, a.w, b.x, b.y, b.z, b.w};
    WPair r;
#pragma unroll
    for (int j = 0; j < 8; j++) {
        ushort_t hh = bf16r(vv[j]);
        r.h[j] = (short)hh;
        r.l[j] = (short)bf16r(vv[j] - f32up(hh));
    }
    return r;
}
// load hi/lo split of 8 fp32 weights into two NAMED vars, pin both in AGPRs.
// Named vars (no arrays) -> no SROA hazard; asm def -> no remat; "a" class ->
// outside the VGPR allocator's spill heuristic.
#define LOADW(H, L, P)                                                          \
    { WPair _t = wsplit(P); H = _t.h; L = _t.l;                                 \
      asm volatile("" : "+a"(H), "+a"(L)); }

// x -> bf16 hi/lo split (once per launch)
__global__ __launch_bounds__(256)
void prep_x(const float* __restrict__ xx, ushort_t* __restrict__ xh,
            ushort_t* __restrict__ xl, int n4) {
    int i = blockIdx.x * 256 + threadIdx.x;
    const int stride = gridDim.x * 256;
    for (; i < n4; i += stride) {
        const float4 v = ((const float4*)xx)[i];
        float a[4] = {v.x, v.y, v.z, v.w};
        ushort_t h[4], l[4];
#pragma unroll
        for (int j = 0; j < 4; j++) { h[j] = bf16r(a[j]); l[j] = bf16r(a[j] - f32up(h[j])); }
        ushort4 hv = {h[0], h[1], h[2], h[3]};
        ushort4 lv = {l[0], l[1], l[2], l[3]};
        ((ushort4*)xh)[i] = hv;
        ((ushort4*)xl)[i] = lv;
    }
}

// Fused 2-layer LSTM scan via MFMA, batch(16) = M dim. Grid: 24 WGs x 512 thr.
//  bid 0..7  = L0 WG w: owns h1[w*32..+32). waves v: q=v>>1, half=v&1,
//              N-tile n0=q*256+w*32+half*16. K=256(h1_{t-1})+128(x_t).
//  bid 8..23 = L1 WG w2: owns h2[w2*16..+16). waves v: q=v&3, kh=v>>2,
//              kh=0: Whh1 over h2_{t-1} (+b1), kh=1: Wih1 over h1_t; LDS join.
// Split-bf16 (3 MFMAs/tile): Ah*Bh + Al*Bh + Ah*Bl ~ fp32 accuracy.
// Weights live in AGPRs (pinned); A-side h/x fragments streamed from L2.
__global__ __launch_bounds__(512, 1)
void lstm_mfma(const float* __restrict__ Wih0, const float* __restrict__ Whh0,
               const float* __restrict__ b0v,
               const float* __restrict__ Wih1, const float* __restrict__ Whh1,
               const float* __restrict__ b1v,
               const ushort_t* __restrict__ xh, const ushort_t* __restrict__ xl,
               ushort_t* h1h, ushort_t* h1l, ushort_t* h2h, ushort_t* h2l,
               float* out, int* cnt0, int* cnt1)
{
    const int tid = threadIdx.x;
    const int lane = tid & 63;
    const int v = tid >> 6;        // wave 0..7
    const int ln15 = lane & 15;    // M (batch) / N (gate-col) index within tile
    const int kgrp = lane >> 4;    // 0..3
    const int bid = blockIdx.x;

    __shared__ float gates0[4][16][33];   // L0: [gate][batch][j-local] (+pad)
    __shared__ float part1[4][16][17];    // L1: kh=1 partials (+pad)
    __shared__ float gates1[4][16][17];   // L1 (+pad)

    if (bid < 8) {
        // ----------------------------- layer 0 -----------------------------
        const int w = bid;
        const int q = v >> 1, half = v & 1;
        const int n0 = q * 256 + w * 32 + half * 16;
        const int nrow = n0 + ln15;

        bf16x8 Wh0,Wh1,Wh2,Wh3,Wh4,Wh5,Wh6,Wh7;      // Whh0 hi (K=256)
        bf16x8 Wl0,Wl1,Wl2,Wl3,Wl4,Wl5,Wl6,Wl7;      // Whh0 lo
        bf16x8 Xh0,Xh1,Xh2,Xh3;                      // Wih0 hi (K=128)
        bf16x8 Xl0,Xl1,Xl2,Xl3;                      // Wih0 lo
        {
            const float* wr = Whh0 + (size_t)nrow * HH + kgrp * 8;
            LOADW(Wh0, Wl0, wr + 0*32); LOADW(Wh1, Wl1, wr + 1*32);
            LOADW(Wh2, Wl2, wr + 2*32); LOADW(Wh3, Wl3, wr + 3*32);
            LOADW(Wh4, Wl4, wr + 4*32); LOADW(Wh5, Wl5, wr + 5*32);
            LOADW(Wh6, Wl6, wr + 6*32); LOADW(Wh7, Wl7, wr + 7*32);
            const float* xr = Wih0 + (size_t)nrow * II + kgrp * 8;
            LOADW(Xh0, Xl0, xr + 0*32); LOADW(Xh1, Xl1, xr + 1*32);
            LOADW(Xh2, Xl2, xr + 2*32); LOADW(Xh3, Xl3, xr + 3*32);
        }
        const float bias = b0v[nrow];

        float c_reg = 0.f;  // c-update: thread (b=tid>>5, jl=tid&31)

        for (int t = 0; t < TT; t++) {
            const int slot = t & (RING - 1);
            const int pslot = (t - 1) & (RING - 1);
            f32x4 acc = {bias, bias, bias, bias};

            // x contribution (independent of recurrence)
            {
                const size_t xb = ((size_t)ln15 * TT + t) * II + kgrp * 8;
#define L0X(KS, XH, XL)                                                         \
                { bf16x8 ah = *(const bf16x8*)(xh + xb + KS*32);                \
                  bf16x8 al = *(const bf16x8*)(xl + xb + KS*32);                \
                  MFA(acc, ah, XH); MFA(acc, al, XH); MFA(acc, ah, XL); }
                L0X(0, Xh0, Xl0) L0X(1, Xh1, Xl1)
                L0X(2, Xh2, Xl2) L0X(3, Xh3, Xl3)
#undef L0X
            }
            if (t >= RING) poll_ge(cnt1 + (t - RING), 16);  // ring backpressure
            if (t > 0) {
                poll_ge(cnt0 + t - 1, 8);
                const size_t hb = ((size_t)pslot * BQ + ln15) * HH + kgrp * 8;
#define L0H(KS, WH, WL)                                                         \
                { bf16x8 ah = *(const bf16x8*)(h1h + hb + KS*32);               \
                  bf16x8 al = *(const bf16x8*)(h1l + hb + KS*32);               \
                  MFA(acc, ah, WH); MFA(acc, al, WH); MFA(acc, ah, WL); }
                L0H(0, Wh0, Wl0) L0H(1, Wh1, Wl1)
                L0H(2, Wh2, Wl2) L0H(3, Wh3, Wl3)
                L0H(4, Wh4, Wl4) L0H(5, Wh5, Wl5)
                L0H(6, Wh6, Wl6) L0H(7, Wh7, Wl7)
#undef L0H
            }
            // activate; D: row(batch)=kgrp*4+r, col(gate)=n0+ln15
#pragma unroll
            for (int r = 0; r < 4; r++) {
                float a = acc[r];
                a = (q == 2) ? tanhf(a) : sigmoidf_(a);
                gates0[q][kgrp * 4 + r][half * 16 + ln15] = a;
            }
            __syncthreads();
            {
                const int b = tid >> 5, jl = tid & 31;
                const float iv = gates0[0][b][jl];
                const float fv = gates0[1][b][jl];
                const float gv = gates0[2][b][jl];
                const float ov = gates0[3][b][jl];
                c_reg = fmaf(fv, c_reg, iv * gv);
                const float hv = ov * tanhf(c_reg);
                const ushort_t hh = bf16r(hv);
                const ushort_t hl = bf16r(hv - f32up(hh));
                const size_t off = ((size_t)slot * BQ + b) * HH + w * 32 + jl;
                h1h[off] = hh;
                h1l[off] = hl;
            }
            __syncthreads();
            if (tid == 0)
                __hip_atomic_fetch_add(cnt0 + t, 1, __ATOMIC_RELEASE, __HIP_MEMORY_SCOPE_AGENT);
        }
    } else {
        // ----------------------------- layer 1 -----------------------------
        const int w2 = bid - 8;
        const int q = v & 3, kh = v >> 2;
        const int n0 = q * 256 + w2 * 16;
        const int nrow = n0 + ln15;

        bf16x8 Fh0,Fh1,Fh2,Fh3,Fh4,Fh5,Fh6,Fh7;
        bf16x8 Fl0,Fl1,Fl2,Fl3,Fl4,Fl5,Fl6,Fl7;
        {
            const float* wr = (kh ? Wih1 : Whh1) + (size_t)nrow * HH + kgrp * 8;
            LOADW(Fh0, Fl0, wr + 0*32); LOADW(Fh1, Fl1, wr + 1*32);
            LOADW(Fh2, Fl2, wr + 2*32); LOADW(Fh3, Fl3, wr + 3*32);
            LOADW(Fh4, Fl4, wr + 4*32); LOADW(Fh5, Fl5, wr + 5*32);
            LOADW(Fh6, Fl6, wr + 6*32); LOADW(Fh7, Fl7, wr + 7*32);
        }
        const float bias = kh ? 0.f : b1v[nrow];

        float c_reg = 0.f;  // c-update: tid<256, (b=tid>>4, jl=tid&15)

        for (int t = 0; t < TT; t++) {
            const int slot = t & (RING - 1);
            const int pslot = (t - 1) & (RING - 1);
            f32x4 acc = {bias, bias, bias, bias};

            if (kh) {
                poll_ge(cnt0 + t, 8);
                const size_t hb = ((size_t)slot * BQ + ln15) * HH + kgrp * 8;
#define L1H(KS, FH, FL)                                                         \
                { bf16x8 ah = *(const bf16x8*)(h1h + hb + KS*32);               \
                  bf16x8 al = *(const bf16x8*)(h1l + hb + KS*32);               \
                  MFA(acc, ah, FH); MFA(acc, al, FH); MFA(acc, ah, FL); }
                L1H(0, Fh0, Fl0) L1H(1, Fh1, Fl1)
                L1H(2, Fh2, Fl2) L1H(3, Fh3, Fl3)
                L1H(4, Fh4, Fl4) L1H(5, Fh5, Fl5)
                L1H(6, Fh6, Fl6) L1H(7, Fh7, Fl7)
#undef L1H
#pragma unroll
                for (int r = 0; r < 4; r++) part1[q][kgrp * 4 + r][ln15] = acc[r];
            } else if (t > 0) {
                poll_ge(cnt1 + t - 1, 16);
                const size_t hb = ((size_t)pslot * BQ + ln15) * HH + kgrp * 8;
#define L1P(KS, FH, FL)                                                         \
                { bf16x8 ah = *(const bf16x8*)(h2h + hb + KS*32);               \
                  bf16x8 al = *(const bf16x8*)(h2l + hb + KS*32);               \
                  MFA(acc, ah, FH); MFA(acc, al, FH); MFA(acc, ah, FL); }
                L1P(0, Fh0, Fl0) L1P(1, Fh1, Fl1)
                L1P(2, Fh2, Fl2) L1P(3, Fh3, Fl3)
                L1P(4, Fh4, Fl4) L1P(5, Fh5, Fl5)
                L1P(6, Fh6, Fl6) L1P(7, Fh7, Fl7)
#undef L1P
            }
            __syncthreads();
            if (!kh) {
#pragma unroll
                for (int r = 0; r < 4; r++) {
                    float a = acc[r] + part1[q][kgrp * 4 + r][ln15];
                    a = (q == 2) ? tanhf(a) : sigmoidf_(a);
                    gates1[q][kgrp * 4 + r][ln15] = a;
                }
            }
            __syncthreads();
            if (tid < 256) {
                const int b = tid >> 4, jl = tid & 15;
                const float iv = gates1[0][b][jl];
                const float fv = gates1[1][b][jl];
                const float gv = gates1[2][b][jl];
                const float ov = gates1[3][b][jl];
                c_reg = fmaf(fv, c_reg, iv * gv);
                const float hv = ov * tanhf(c_reg);
                out[((size_t)b * TT + t) * HH + w2 * 16 + jl] = hv;
                const ushort_t hh = bf16r(hv);
                const ushort_t hl = bf16r(hv - f32up(hh));
                const size_t off = ((size_t)slot * BQ + b) * HH + w2 * 16 + jl;
                h2h[off] = hh;
                h2l[off] = hl;
            }
            __syncthreads();
            if (tid == 0)
                __hip_atomic_fetch_add(cnt1 + t, 1, __ATOMIC_RELEASE, __HIP_MEMORY_SCOPE_AGENT);
        }
    }
}

extern "C" void kernel_launch(void* const* d_in, const int* in_sizes, int n_in,
                              void* d_out, int out_size, void* d_ws, size_t ws_size,
                              hipStream_t stream) {
    (void)in_sizes; (void)n_in; (void)out_size; (void)ws_size;
    const float* x    = (const float*)d_in[0];
    const float* Wih0 = (const float*)d_in[1];
    const float* Whh0 = (const float*)d_in[2];
    const float* b0   = (const float*)d_in[3];
    const float* Wih1 = (const float*)d_in[4];
    const float* Whh1 = (const float*)d_in[5];
    const float* b1   = (const float*)d_in[6];
    float* out = (float*)d_out;

    // ---- workspace carve (~42 MB) ----
    char* ws = (char*)d_ws;
    int* cnt0 = (int*)ws;                               // [TT]
    int* cnt1 = cnt0 + TT;                              // [TT]
    ushort_t* xh  = (ushort_t*)(cnt1 + TT);             // [BQ][TT][II]
    ushort_t* xl  = xh + (size_t)BQ * TT * II;
    ushort_t* h1h = xl + (size_t)BQ * TT * II;          // [RING][BQ][HH]
    ushort_t* h1l = h1h + (size_t)RING * BQ * HH;
    ushort_t* h2h = h1l + (size_t)RING * BQ * HH;
    ushort_t* h2l = h2h + (size_t)RING * BQ * HH;

    hipMemsetAsync(cnt0, 0, 2 * TT * sizeof(int), stream);
    prep_x<<<2048, 256, 0, stream>>>(x, xh, xl, BQ * TT * II / 4);
    lstm_mfma<<<24, 512, 0, stream>>>(Wih0, Whh0, b0, Wih1, Whh1, b1,
                                      xh, xl, h1h, h1l, h2h, h2l,
                                      out, cnt0, cnt1);
}

// Round 7
// 17765.471 us; speedup vs baseline: 1.7877x; 1.7603x over previous
//
#include <hip/hip_runtime.h>
#include <hip/hip_bf16.h>
#include <stdint.h>

#define BQ 16      // batch
#define TT 4096    // timesteps
#define II 128     // input features
#define HH 256     // hidden
#define RING 256   // h-ring slots (power of 2)
#define SEQPAD 32  // ints per seq word (128B line)

typedef __attribute__((ext_vector_type(8))) short bf16x8;  // 8 bf16 (4 regs)
typedef __attribute__((ext_vector_type(4))) float f32x4;   // MFMA acc
typedef unsigned short ushort_t;
typedef unsigned long long u64t;

__device__ __forceinline__ float sigmoidf_(float x) { return 1.0f / (1.0f + __expf(-x)); }

__device__ __forceinline__ ushort_t bf16r(float x) {
    __hip_bfloat16 h = __float2bfloat16(x);       // RTN
    union { __hip_bfloat16 h; ushort_t u; } c; c.h = h; return c.u;
}
__device__ __forceinline__ float f32up(ushort_t u) {
    union { unsigned int i; float f; } c; c.i = ((unsigned int)u) << 16; return c.f;
}

// relaxed agent-scope coherent accesses: sc-flagged, NO cache-maintenance fences
__device__ __forceinline__ u64t ldg64(const ushort_t* p) {
    return __hip_atomic_load((const u64t*)p, __ATOMIC_RELAXED, __HIP_MEMORY_SCOPE_AGENT);
}
__device__ __forceinline__ void stg64(ushort_t* p, u64t v) {
    __hip_atomic_store((u64t*)p, v, __ATOMIC_RELAXED, __HIP_MEMORY_SCOPE_AGENT);
}

// MFMA with B pinned in AGPR (gfx950: A,B may source from AGPR).
#define MFA(ACC, A, B)                                                          \
    asm volatile("v_mfma_f32_16x16x32_bf16 %0, %1, %2, %0"                      \
                 : "+v"(ACC) : "v"(A), "a"(B))

struct WPair { bf16x8 h, l; };
__device__ __forceinline__ WPair wsplit(const float* p) {
    float4 a = *(const float4*)p;
    float4 b = *(const float4*)(p + 4);
    float vv[8] = {a.x, a.y, a.z, a.w, b.x, b.y, b.z, b.w};
    WPair r;
#pragma unroll
    for (int j = 0; j < 8; j++) {
        ushort_t hh = bf16r(vv[j]);
        r.h[j] = (short)hh;
        r.l[j] = (short)bf16r(vv[j] - f32up(hh));
    }
    return r;
}
#define LOADW(H, L, P)                                                          \
    { WPair _t = wsplit(P); H = _t.h; L = _t.l;                                 \
      asm volatile("" : "+a"(H), "+a"(L)); }

// x -> bf16 hi/lo split (once per launch)
__global__ __launch_bounds__(256)
void prep_x(const float* __restrict__ xx, ushort_t* __restrict__ xh,
            ushort_t* __restrict__ xl, int n4) {
    int i = blockIdx.x * 256 + threadIdx.x;
    const int stride = gridDim.x * 256;
    for (; i < n4; i += stride) {
        const float4 v = ((const float4*)xx)[i];
        float a[4] = {v.x, v.y, v.z, v.w};
        ushort_t h[4], l[4];
#pragma unroll
        for (int j = 0; j < 4; j++) { h[j] = bf16r(a[j]); l[j] = bf16r(a[j] - f32up(h[j])); }
        ushort4 hv = {h[0], h[1], h[2], h[3]};
        ushort4 lv = {l[0], l[1], l[2], l[3]};
        ((ushort4*)xh)[i] = hv;
        ((ushort4*)xl)[i] = lv;
    }
}

// Stage one ring slot (hi,lo; 16x256 bf16 each) into LDS in MFMA-fragment
// order: halfword index = ks*512 + lane*8 gives lane-linear ds_read_b128.
// Element (b,k): ks=k>>5, kgrp=(k>>3)&3, lane=kgrp*16+b, j=k&7.
__device__ __forceinline__ void stage_h(const ushort_t* gh, const ushort_t* gl,
                                        ushort_t* sH, ushort_t* sL, int tid) {
#pragma unroll
    for (int r = 0; r < 2; r++) {
        const int m = tid + r * 512;          // u64 index 0..1023
        const int b = m >> 6, k4 = m & 63;
        const int idx = (k4 >> 3) * 512 + (((k4 >> 1) & 3) * 16 + b) * 8 + (k4 & 1) * 4;
        u64t vh = ldg64(gh + m * 4);
        u64t vl = ldg64(gl + m * 4);
        *(u64t*)(sH + idx) = vh;
        *(u64t*)(sL + idx) = vl;
    }
}

// Wave 0 polls producer seq words (relaxed; each in its own 128B line).
__device__ __forceinline__ void pollpair(const int* s0, const int* s1, int lane,
                                         int need0, int need1) {
    const int* ap = (lane < 8)  ? (s0 + lane * SEQPAD)
                  : (lane < 16) ? (s1 + (lane - 8) * SEQPAD) : s0;
    const int need = (lane < 8) ? need0 : (lane < 16) ? need1 : 0;
    while (true) {
        int vv = __hip_atomic_load(ap, __ATOMIC_RELAXED, __HIP_MEMORY_SCOPE_AGENT);
        if (__all(vv >= need)) break;
        __builtin_amdgcn_s_sleep(2);
    }
    asm volatile("" ::: "memory");
}

// Fused 2-layer LSTM scan via MFMA, batch(16)=M. Grid: 16 WGs x 512 thr.
//  bid 0..7  = L0 WG w: owns h1[w*32..+32). waves v: q=v>>1, half=v&1.
//              K = 256 (h1_{t-1}, LDS-staged) + 128 (x_t, cached global).
//  bid 8..15 = L1 WG w2: owns h2[w2*32..+32). waves v: q=v&3, half=v>>2.
//              Each wave holds BOTH Whh1 (over h2_{t-1}) and Wih1 (over h1_t).
// Split-bf16 (3 MFMAs/tile). Weights in AGPRs. Sync: per-WG seq words,
// relaxed agent atomics only (no acquire/release -> no L2 inv/wb storms);
// producer order via __syncthreads' vmcnt(0) drain, then lane0 seq store.
__global__ __launch_bounds__(512, 1)
void lstm_mfma(const float* __restrict__ Wih0, const float* __restrict__ Whh0,
               const float* __restrict__ b0v,
               const float* __restrict__ Wih1, const float* __restrict__ Whh1,
               const float* __restrict__ b1v,
               const ushort_t* __restrict__ xh, const ushort_t* __restrict__ xl,
               ushort_t* h1h, ushort_t* h1l, ushort_t* h2h, ushort_t* h2l,
               float* out, int* seq0, int* seq1)
{
    const int tid = threadIdx.x;
    const int lane = tid & 63;
    const int v = tid >> 6;        // wave 0..7
    const int ln15 = lane & 15;
    const int kgrp = lane >> 4;
    const int bid = blockIdx.x;
    const int lofs = lane * 8;

    __shared__ ushort_t sAH[4096], sAL[4096];   // staged h (fragment order)
    __shared__ ushort_t sBH[4096], sBL[4096];   // L1: staged h2_prev
    __shared__ float gatesS[4][16][33];         // [gate][batch][local col]

    if (bid < 8) {
        // ----------------------------- layer 0 -----------------------------
        const int w = bid;
        const int q = v >> 1, half = v & 1;
        const int n0 = q * 256 + w * 32 + half * 16;
        const int nrow = n0 + ln15;

        bf16x8 Wh0,Wh1,Wh2,Wh3,Wh4,Wh5,Wh6,Wh7;   // Whh0 hi (K=256)
        bf16x8 Wl0,Wl1,Wl2,Wl3,Wl4,Wl5,Wl6,Wl7;   // Whh0 lo
        bf16x8 Xh0,Xh1,Xh2,Xh3, Xl0,Xl1,Xl2,Xl3;  // Wih0 hi/lo (K=128)
        {
            const float* wr = Whh0 + (size_t)nrow * HH + kgrp * 8;
            LOADW(Wh0, Wl0, wr + 0*32); LOADW(Wh1, Wl1, wr + 1*32);
            LOADW(Wh2, Wl2, wr + 2*32); LOADW(Wh3, Wl3, wr + 3*32);
            LOADW(Wh4, Wl4, wr + 4*32); LOADW(Wh5, Wl5, wr + 5*32);
            LOADW(Wh6, Wl6, wr + 6*32); LOADW(Wh7, Wl7, wr + 7*32);
            const float* xr = Wih0 + (size_t)nrow * II + kgrp * 8;
            LOADW(Xh0, Xl0, xr + 0*32); LOADW(Xh1, Xl1, xr + 1*32);
            LOADW(Xh2, Xl2, xr + 2*32); LOADW(Xh3, Xl3, xr + 3*32);
        }
        const float bias = b0v[nrow];
        float c4[4] = {0.f, 0.f, 0.f, 0.f};

        for (int t = 0; t < TT; t++) {
            const int slot = t & (RING - 1);
            const int pslot = (t - 1) & (RING - 1);
            f32x4 accx = {bias, bias, bias, bias};
            f32x4 acc0 = {0,0,0,0}, acc1 = {0,0,0,0};

            // x contribution (cached loads; off the sync critical path)
            {
                const size_t xb = ((size_t)ln15 * TT + t) * II + kgrp * 8;
#define L0X(KS, XH, XL)                                                         \
                { bf16x8 ah = *(const bf16x8*)(xh + xb + KS*32);                \
                  bf16x8 al = *(const bf16x8*)(xl + xb + KS*32);                \
                  MFA(accx, ah, XH); MFA(accx, al, XH); MFA(accx, ah, XL); }
                L0X(0, Xh0, Xl0) L0X(1, Xh1, Xl1)
                L0X(2, Xh2, Xl2) L0X(3, Xh3, Xl3)
#undef L0X
            }
            if (t > 0 && v == 0)
                pollpair(seq0, seq1, lane, t, (t >= RING) ? t - RING + 1 : 0);
            __syncthreads();
            if (t > 0)
                stage_h(h1h + (size_t)pslot * BQ * HH, h1l + (size_t)pslot * BQ * HH,
                        sAH, sAL, tid);
            __syncthreads();
            if (t > 0) {
#define L0H(KS, WH, WL, ACC)                                                    \
                { bf16x8 ah = *(const bf16x8*)(sAH + KS*512 + lofs);            \
                  bf16x8 al = *(const bf16x8*)(sAL + KS*512 + lofs);            \
                  MFA(ACC, ah, WH); MFA(ACC, al, WH); MFA(ACC, ah, WL); }
                L0H(0, Wh0, Wl0, acc0) L0H(1, Wh1, Wl1, acc1)
                L0H(2, Wh2, Wl2, acc0) L0H(3, Wh3, Wl3, acc1)
                L0H(4, Wh4, Wl4, acc0) L0H(5, Wh5, Wl5, acc1)
                L0H(6, Wh6, Wl6, acc0) L0H(7, Wh7, Wl7, acc1)
#undef L0H
            }
#pragma unroll
            for (int r = 0; r < 4; r++) {
                float a = accx[r] + acc0[r] + acc1[r];
                a = (q == 2) ? tanhf(a) : sigmoidf_(a);
                gatesS[q][kgrp * 4 + r][half * 16 + ln15] = a;
            }
            __syncthreads();
            if (tid < 128) {
                const int b = tid >> 3, j4 = (tid & 7) * 4;
                u64t Hh = 0, Hl = 0;
#pragma unroll
                for (int e = 0; e < 4; e++) {
                    const float iv = gatesS[0][b][j4 + e];
                    const float fv = gatesS[1][b][j4 + e];
                    const float gv = gatesS[2][b][j4 + e];
                    const float ov = gatesS[3][b][j4 + e];
                    c4[e] = fmaf(fv, c4[e], iv * gv);
                    const float hv = ov * tanhf(c4[e]);
                    const ushort_t hh = bf16r(hv);
                    const ushort_t hl = bf16r(hv - f32up(hh));
                    Hh |= (u64t)hh << (16 * e);
                    Hl |= (u64t)hl << (16 * e);
                }
                const size_t off = ((size_t)slot * BQ + b) * HH + w * 32 + j4;
                stg64(h1h + off, Hh);
                stg64(h1l + off, Hl);
            }
            __syncthreads();   // drains vmcnt(0) per wave -> stores globally acked
            if (tid == 0)
                __hip_atomic_store(seq0 + w * SEQPAD, t + 1,
                                   __ATOMIC_RELAXED, __HIP_MEMORY_SCOPE_AGENT);
        }
    } else {
        // ----------------------------- layer 1 -----------------------------
        const int w2 = bid - 8;
        const int q = v & 3, half = v >> 2;
        const int n0 = q * 256 + w2 * 32 + half * 16;
        const int nrow = n0 + ln15;

        bf16x8 Hh0,Hh1,Hh2,Hh3,Hh4,Hh5,Hh6,Hh7;   // Whh1 hi
        bf16x8 Hl0,Hl1,Hl2,Hl3,Hl4,Hl5,Hl6,Hl7;   // Whh1 lo
        bf16x8 Ih0,Ih1,Ih2,Ih3,Ih4,Ih5,Ih6,Ih7;   // Wih1 hi
        bf16x8 Il0,Il1,Il2,Il3,Il4,Il5,Il6,Il7;   // Wih1 lo
        {
            const float* wr = Whh1 + (size_t)nrow * HH + kgrp * 8;
            LOADW(Hh0, Hl0, wr + 0*32); LOADW(Hh1, Hl1, wr + 1*32);
            LOADW(Hh2, Hl2, wr + 2*32); LOADW(Hh3, Hl3, wr + 3*32);
            LOADW(Hh4, Hl4, wr + 4*32); LOADW(Hh5, Hl5, wr + 5*32);
            LOADW(Hh6, Hl6, wr + 6*32); LOADW(Hh7, Hl7, wr + 7*32);
            const float* ir = Wih1 + (size_t)nrow * HH + kgrp * 8;
            LOADW(Ih0, Il0, ir + 0*32); LOADW(Ih1, Il1, ir + 1*32);
            LOADW(Ih2, Il2, ir + 2*32); LOADW(Ih3, Il3, ir + 3*32);
            LOADW(Ih4, Il4, ir + 4*32); LOADW(Ih5, Il5, ir + 5*32);
            LOADW(Ih6, Il6, ir + 6*32); LOADW(Ih7, Il7, ir + 7*32);
        }
        const float bias = b1v[nrow];
        float c4[4] = {0.f, 0.f, 0.f, 0.f};

        for (int t = 0; t < TT; t++) {
            const int slot = t & (RING - 1);
            const int pslot = (t - 1) & (RING - 1);
            if (v == 0) pollpair(seq0, seq1, lane, t + 1, t);
            __syncthreads();
            stage_h(h1h + (size_t)slot * BQ * HH, h1l + (size_t)slot * BQ * HH,
                    sAH, sAL, tid);
            if (t > 0)
                stage_h(h2h + (size_t)pslot * BQ * HH, h2l + (size_t)pslot * BQ * HH,
                        sBH, sBL, tid);
            __syncthreads();

            f32x4 accB = {bias, bias, bias, bias};
            f32x4 a0 = {0,0,0,0}, a1 = {0,0,0,0}, a2 = {0,0,0,0};
#define L1T(KS, SH, SL, WH, WL, ACC)                                            \
            { bf16x8 ah = *(const bf16x8*)(SH + KS*512 + lofs);                 \
              bf16x8 al = *(const bf16x8*)(SL + KS*512 + lofs);                 \
              MFA(ACC, ah, WH); MFA(ACC, al, WH); MFA(ACC, ah, WL); }
            // Wih1 over h1_t
            L1T(0, sAH, sAL, Ih0, Il0, accB) L1T(1, sAH, sAL, Ih1, Il1, a0)
            L1T(2, sAH, sAL, Ih2, Il2, accB) L1T(3, sAH, sAL, Ih3, Il3, a0)
            L1T(4, sAH, sAL, Ih4, Il4, accB) L1T(5, sAH, sAL, Ih5, Il5, a0)
            L1T(6, sAH, sAL, Ih6, Il6, accB) L1T(7, sAH, sAL, Ih7, Il7, a0)
            if (t > 0) {
                // Whh1 over h2_{t-1}
                L1T(0, sBH, sBL, Hh0, Hl0, a1) L1T(1, sBH, sBL, Hh1, Hl1, a2)
                L1T(2, sBH, sBL, Hh2, Hl2, a1) L1T(3, sBH, sBL, Hh3, Hl3, a2)
                L1T(4, sBH, sBL, Hh4, Hl4, a1) L1T(5, sBH, sBL, Hh5, Hl5, a2)
                L1T(6, sBH, sBL, Hh6, Hl6, a1) L1T(7, sBH, sBL, Hh7, Hl7, a2)
            }
#undef L1T
#pragma unroll
            for (int r = 0; r < 4; r++) {
                float a = accB[r] + a0[r] + a1[r] + a2[r];
                a = (q == 2) ? tanhf(a) : sigmoidf_(a);
                gatesS[q][kgrp * 4 + r][half * 16 + ln15] = a;
            }
            __syncthreads();
            if (tid < 128) {
                const int b = tid >> 3, j4 = (tid & 7) * 4;
                u64t Hh = 0, Hl = 0;
                float hv4[4];
#pragma unroll
                for (int e = 0; e < 4; e++) {
                    const float iv = gatesS[0][b][j4 + e];
                    const float fv = gatesS[1][b][j4 + e];
                    const float gv = gatesS[2][b][j4 + e];
                    const float ov = gatesS[3][b][j4 + e];
                    c4[e] = fmaf(fv, c4[e], iv * gv);
                    const float hv = ov * tanhf(c4[e]);
                    hv4[e] = hv;
                    const ushort_t hh = bf16r(hv);
                    const ushort_t hl = bf16r(hv - f32up(hh));
                    Hh |= (u64t)hh << (16 * e);
                    Hl |= (u64t)hl << (16 * e);
                }
                float4 o4 = {hv4[0], hv4[1], hv4[2], hv4[3]};
                *(float4*)(out + ((size_t)b * TT + t) * HH + w2 * 32 + j4) = o4;
                const size_t off = ((size_t)slot * BQ + b) * HH + w2 * 32 + j4;
                stg64(h2h + off, Hh);
                stg64(h2l + off, Hl);
            }
            __syncthreads();
            if (tid == 0)
                __hip_atomic_store(seq1 + w2 * SEQPAD, t + 1,
                                   __ATOMIC_RELAXED, __HIP_MEMORY_SCOPE_AGENT);
        }
    }
}

extern "C" void kernel_launch(void* const* d_in, const int* in_sizes, int n_in,
                              void* d_out, int out_size, void* d_ws, size_t ws_size,
                              hipStream_t stream) {
    (void)in_sizes; (void)n_in; (void)out_size; (void)ws_size;
    const float* x    = (const float*)d_in[0];
    const float* Wih0 = (const float*)d_in[1];
    const float* Whh0 = (const float*)d_in[2];
    const float* b0   = (const float*)d_in[3];
    const float* Wih1 = (const float*)d_in[4];
    const float* Whh1 = (const float*)d_in[5];
    const float* b1   = (const float*)d_in[6];
    float* out = (float*)d_out;

    // ---- workspace carve (~42 MB) ----
    char* ws = (char*)d_ws;
    int* seq0 = (int*)ws;                               // [8][SEQPAD]
    int* seq1 = seq0 + 8 * SEQPAD;                      // [8][SEQPAD]
    ushort_t* xh  = (ushort_t*)(seq1 + 8 * SEQPAD);     // [BQ][TT][II]
    ushort_t* xl  = xh + (size_t)BQ * TT * II;
    ushort_t* h1h = xl + (size_t)BQ * TT * II;          // [RING][BQ][HH]
    ushort_t* h1l = h1h + (size_t)RING * BQ * HH;
    ushort_t* h2h = h1l + (size_t)RING * BQ * HH;
    ushort_t* h2l = h2h + (size_t)RING * BQ * HH;

    hipMemsetAsync(seq0, 0, 16 * SEQPAD * sizeof(int), stream);
    prep_x<<<2048, 256, 0, stream>>>(x, xh, xl, BQ * TT * II / 4);
    lstm_mfma<<<16, 512, 0, stream>>>(Wih0, Whh0, b0, Wih1, Whh1, b1,
                                      xh, xl, h1h, h1l, h2h, h2l,
                                      out, seq0, seq1);
}

// Round 8
// 15351.929 us; speedup vs baseline: 2.0687x; 1.1572x over previous
//
#include <hip/hip_runtime.h>
#include <hip/hip_bf16.h>
#include <stdint.h>

#define BQ 16
#define TT 4096
#define II 128
#define HH 256
#define RINGN 8
#define SEQPAD 32

typedef __attribute__((ext_vector_type(8))) short bf16x8;  // 8 bf16 (4 regs)
typedef __attribute__((ext_vector_type(4))) float f32x4;
typedef unsigned short ushort_t;
typedef unsigned long long u64t;

union U2 { struct { u64t a, b; } u; bf16x8 v; };

__device__ __forceinline__ ushort_t bf16r(float x) {
    __hip_bfloat16 h = __float2bfloat16(x);
    union { __hip_bfloat16 h; ushort_t u; } c; c.h = h; return c.u;
}
__device__ __forceinline__ float f32up(ushort_t u) {
    union { unsigned int i; float f; } c; c.i = ((unsigned int)u) << 16; return c.f;
}
__device__ __forceinline__ float sigf(float x) {
    return __builtin_amdgcn_rcpf(1.f + __expf(-x));
}
__device__ __forceinline__ float tanhfast(float x) {
    float xc = fminf(fmaxf(x, -15.f), 15.f);
    float e = __expf(2.f * xc);
    return (e - 1.f) * __builtin_amdgcn_rcpf(e + 1.f);
}
// relaxed agent-scope (coherent at MALL, no cache-maintenance fences)
__device__ __forceinline__ u64t ldq(u64t* p) {
    return __hip_atomic_load(p, __ATOMIC_RELAXED, __HIP_MEMORY_SCOPE_AGENT);
}
__device__ __forceinline__ void stq(u64t* p, u64t v) {
    __hip_atomic_store(p, v, __ATOMIC_RELAXED, __HIP_MEMORY_SCOPE_AGENT);
}

#define MFA(ACC, A, B)                                                          \
    asm volatile("v_mfma_f32_16x16x32_bf16 %0, %1, %2, %0"                      \
                 : "+v"(ACC) : "v"(A), "a"(B))
__device__ __forceinline__ f32x4 MFI(bf16x8 a, bf16x8 b, f32x4 c) {
    return __builtin_amdgcn_mfma_f32_16x16x32_bf16(a, b, c, 0, 0, 0);
}

struct WPair { bf16x8 h, l; };
__device__ __forceinline__ WPair wsplit(const float* p) {
    float4 a = *(const float4*)p;
    float4 b = *(const float4*)(p + 4);
    float vv[8] = {a.x, a.y, a.z, a.w, b.x, b.y, b.z, b.w};
    WPair r;
#pragma unroll
    for (int j = 0; j < 8; j++) {
        ushort_t hh = bf16r(vv[j]);
        r.h[j] = (short)hh;
        r.l[j] = (short)bf16r(vv[j] - f32up(hh));
    }
    return r;
}
#define LOADW(H, L, P)                                                          \
    { WPair _t = wsplit(P); H = _t.h; L = _t.l;                                 \
      asm volatile("" : "+a"(H), "+a"(L)); }
#define LOADWH(H, P)                                                            \
    { WPair _t = wsplit(P); H = _t.h; asm volatile("" : "+a"(H)); }

__device__ __forceinline__ void pollwave(const int* seq, int need) {
    const int* p = seq + (threadIdx.x & 7) * SEQPAD;
    while (1) {
        int vv = __hip_atomic_load(p, __ATOMIC_RELAXED, __HIP_MEMORY_SCOPE_AGENT);
        if (__all(vv >= need)) break;
        __builtin_amdgcn_s_sleep(1);
    }
    asm volatile("" ::: "memory");
}

// xw[t_loc][n][b] = b0[n] + sum_k x[b][t][k] * Wih0[n][k]  (split-bf16, ~fp32)
__global__ __launch_bounds__(256, 1)
void xw_gemm(const float* __restrict__ x, const float* __restrict__ Wih0,
             const float* __restrict__ b0v, float* __restrict__ xw,
             int t0, int TC)
{
    const int tid = threadIdx.x, lane = tid & 63, wv = tid >> 6;
    const int ln15 = lane & 15, kgrp = lane >> 4;
    const int tb = blockIdx.x >> 2, quarter = blockIdx.x & 3;
    const int n0 = quarter * 256 + wv * 64;

    bf16x8 w_h[4][4], w_l[4][4];
    float bb[4];
#pragma unroll
    for (int c = 0; c < 4; c++) {
        const int nr = n0 + c * 16 + ln15;
        const float* p = Wih0 + (size_t)nr * II + kgrp * 8;
#pragma unroll
        for (int k = 0; k < 4; k++) {
            WPair t = wsplit(p + k * 32);
            w_h[c][k] = t.h; w_l[c][k] = t.l;
        }
        bb[c] = b0v[nr];
    }
    for (int tt = 0; tt < 8; tt++) {
        const int t = t0 + tb * 8 + tt;
        bf16x8 ah[4], al[4];
#pragma unroll
        for (int k = 0; k < 4; k++) {
            WPair a = wsplit(x + ((size_t)ln15 * TT + t) * II + k * 32 + kgrp * 8);
            ah[k] = a.h; al[k] = a.l;
        }
        f32x4 acc[4];
#pragma unroll
        for (int c = 0; c < 4; c++) acc[c] = (f32x4){bb[c], bb[c], bb[c], bb[c]};
#pragma unroll
        for (int k = 0; k < 4; k++)
#pragma unroll
            for (int c = 0; c < 4; c++) {
                acc[c] = MFI(ah[k], w_h[c][k], acc[c]);
                acc[c] = MFI(al[k], w_h[c][k], acc[c]);
                acc[c] = MFI(ah[k], w_l[c][k], acc[c]);
            }
#pragma unroll
        for (int c = 0; c < 4; c++)
            *(f32x4*)(xw + (((size_t)(t - t0) * 1024) + n0 + c * 16 + ln15) * 16 + kgrp * 4) = acc[c];
    }
}

// Fused 2-layer scan. 8 WGs x 512 thr; WG w owns h1/h2 slice [w*32, w*32+32).
// Wave v<4: L0 compute (quad=v>>1, kh=v&1) + hosts the update phase.
// Wave v>=4: L1 compute (one step behind: t1 = s-1).
// Each wave: K-quarter of 4 tiles (qq in {2quad,2quad+1} x cc in {0,1});
// A-frags loaded DIRECTLY from fragment-ordered rings via relaxed sc1 u64
// loads (one read per byte per WG; no LDS staging). Partials join in gP LDS.
// Sync: per-WG seq word; store->barrier(vmcnt drain)->seq; consumers poll.
__global__ __launch_bounds__(512, 2)
void lstm_ring(const float* __restrict__ Whh0, const float* __restrict__ Wih1,
               const float* __restrict__ Whh1, const float* __restrict__ b1v,
               const float* __restrict__ xw,
               u64t* r1h, u64t* r1l, u64t* r2h, u64t* r2l,
               float* out, float* c0s, float* c1s, int* seq,
               int t0, int tEnd)
{
    const int tid = threadIdx.x;
    const int lane = tid & 63;
    const int v = tid >> 6;
    const int ln15 = lane & 15, kgrp = lane >> 4;
    const int w = blockIdx.x;

    __shared__ float gP[2][2][4][16][33];  // [layer][khalf][gate][batch][col]

    if (v < 4) {
        // ---------------- L0 compute + update host ----------------
        const int quad = v >> 1, kh = v & 1;
        const int qA = quad * 2, qB = quad * 2 + 1;
        const int r0 = qA * 256 + w * 32 + 0  + ln15;
        const int r1 = qA * 256 + w * 32 + 16 + ln15;
        const int r2 = qB * 256 + w * 32 + 0  + ln15;
        const int r3 = qB * 256 + w * 32 + 16 + ln15;

        bf16x8 B0h0,B0h1,B0h2,B0h3, B0l0,B0l1,B0l2,B0l3;
        bf16x8 B1h0,B1h1,B1h2,B1h3, B1l0,B1l1,B1l2,B1l3;
        bf16x8 B2h0,B2h1,B2h2,B2h3, B2l0,B2l1,B2l2,B2l3;
        bf16x8 B3h0,B3h1,B3h2,B3h3, B3l0,B3l1,B3l2,B3l3;
#define LW0(T, RT)                                                              \
        { const float* p = Whh0 + (size_t)(RT) * HH + kh * 128 + kgrp * 8;      \
          LOADW(B##T##h0, B##T##l0, p);      LOADW(B##T##h1, B##T##l1, p + 32); \
          LOADW(B##T##h2, B##T##l2, p + 64); LOADW(B##T##h3, B##T##l3, p + 96); }
        LW0(0, r0) LW0(1, r1) LW0(2, r2) LW0(3, r3)
#undef LW0

        float c4[4] = {0.f, 0.f, 0.f, 0.f};
        {
            const int ut = tid & 127;
            const int b = ut >> 3, j4v = (ut & 7) * 4;
            const float* cs = (tid < 128) ? c0s : c1s;
            if (tid < 256) {
                f32x4 cv = *(const f32x4*)(cs + (size_t)b * HH + w * 32 + j4v);
                c4[0]=cv[0]; c4[1]=cv[1]; c4[2]=cv[2]; c4[3]=cv[3];
            }
        }

        for (int s = t0; s < tEnd; s++) {
            if (s < TT) {
                f32x4 a0, a1, a2, a3;
                if (kh == 0) {
                    const size_t xb = ((size_t)(s - t0) * 1024);
                    a0 = *(const f32x4*)(xw + (xb + r0) * 16 + kgrp * 4);
                    a1 = *(const f32x4*)(xw + (xb + r1) * 16 + kgrp * 4);
                    a2 = *(const f32x4*)(xw + (xb + r2) * 16 + kgrp * 4);
                    a3 = *(const f32x4*)(xw + (xb + r3) * 16 + kgrp * 4);
                } else {
                    a0 = (f32x4){0,0,0,0}; a1 = a0; a2 = a0; a3 = a0;
                }
                if (s > 0) {
                    pollwave(seq, s);
                    const size_t rb = (size_t)((s - 1) & (RINGN - 1)) * 1024
                                    + (size_t)(kgrp * 16 + ln15) * 2;
                    U2 Ah0, Ah1, Ah2, Ah3, Al0, Al1, Al2, Al3;
#define RL0(k)                                                                  \
                    { const size_t o = rb + (size_t)(kh * 4 + k) * 128;         \
                      Ah##k.u.a = ldq(r1h + o); Ah##k.u.b = ldq(r1h + o + 1);   \
                      Al##k.u.a = ldq(r1l + o); Al##k.u.b = ldq(r1l + o + 1); }
                    RL0(0) RL0(1) RL0(2) RL0(3)
#undef RL0
#define MK0(k)                                                                  \
                    MFA(a0, Ah##k.v, B0h##k); MFA(a0, Al##k.v, B0h##k);         \
                    MFA(a0, Ah##k.v, B0l##k);                                   \
                    MFA(a1, Ah##k.v, B1h##k); MFA(a1, Al##k.v, B1h##k);         \
                    MFA(a1, Ah##k.v, B1l##k);                                   \
                    MFA(a2, Ah##k.v, B2h##k); MFA(a2, Al##k.v, B2h##k);         \
                    MFA(a2, Ah##k.v, B2l##k);                                   \
                    MFA(a3, Ah##k.v, B3h##k); MFA(a3, Al##k.v, B3h##k);         \
                    MFA(a3, Ah##k.v, B3l##k);
                    MK0(0) MK0(1) MK0(2) MK0(3)
#undef MK0
                }
#pragma unroll
                for (int r = 0; r < 4; r++) {
                    gP[0][kh][qA][kgrp * 4 + r][0  + ln15] = a0[r];
                    gP[0][kh][qA][kgrp * 4 + r][16 + ln15] = a1[r];
                    gP[0][kh][qB][kgrp * 4 + r][0  + ln15] = a2[r];
                    gP[0][kh][qB][kgrp * 4 + r][16 + ln15] = a3[r];
                }
            }
            __syncthreads();
            // ---- update phase ----
            if (tid < 128) {
                if (s < TT) {
                    const int b = tid >> 3, j4v = (tid & 7) * 4;
                    u64t Hh = 0, Hl = 0;
#pragma unroll
                    for (int e = 0; e < 4; e++) {
                        const int col = j4v + e;
                        const float pi = gP[0][0][0][b][col] + gP[0][1][0][b][col];
                        const float pf = gP[0][0][1][b][col] + gP[0][1][1][b][col];
                        const float pg = gP[0][0][2][b][col] + gP[0][1][2][b][col];
                        const float po = gP[0][0][3][b][col] + gP[0][1][3][b][col];
                        const float iv = sigf(pi), fv = sigf(pf);
                        const float gv = tanhfast(pg), ov = sigf(po);
                        c4[e] = fmaf(fv, c4[e], iv * gv);
                        const float hv = ov * tanhfast(c4[e]);
                        const ushort_t hh = bf16r(hv);
                        const ushort_t hl = bf16r(hv - f32up(hh));
                        Hh |= (u64t)hh << (16 * e);
                        Hl |= (u64t)hl << (16 * e);
                    }
                    const size_t fo = (size_t)(s & (RINGN - 1)) * 1024 + (size_t)w * 128
                                    + (size_t)((tid >> 1) & 3) * 32
                                    + (size_t)(tid >> 3) * 2 + (tid & 1);
                    stq(r1h + fo, Hh); stq(r1l + fo, Hl);
                }
            } else if (tid < 256) {
                if (s >= 1) {
                    const int tl = tid - 128;
                    const int b = tl >> 3, j4v = (tl & 7) * 4;
                    u64t Hh = 0, Hl = 0;
                    f32x4 ho;
#pragma unroll
                    for (int e = 0; e < 4; e++) {
                        const int col = j4v + e;
                        const float pi = gP[1][0][0][b][col] + gP[1][1][0][b][col];
                        const float pf = gP[1][0][1][b][col] + gP[1][1][1][b][col];
                        const float pg = gP[1][0][2][b][col] + gP[1][1][2][b][col];
                        const float po = gP[1][0][3][b][col] + gP[1][1][3][b][col];
                        const float iv = sigf(pi), fv = sigf(pf);
                        const float gv = tanhfast(pg), ov = sigf(po);
                        c4[e] = fmaf(fv, c4[e], iv * gv);
                        const float hv = ov * tanhfast(c4[e]);
                        ho[e] = hv;
                        const ushort_t hh = bf16r(hv);
                        const ushort_t hl = bf16r(hv - f32up(hh));
                        Hh |= (u64t)hh << (16 * e);
                        Hl |= (u64t)hl << (16 * e);
                    }
                    *(f32x4*)(out + ((size_t)b * TT + (s - 1)) * HH + w * 32 + j4v) = ho;
                    const size_t fo = (size_t)((s - 1) & (RINGN - 1)) * 1024 + (size_t)w * 128
                                    + (size_t)((tl >> 1) & 3) * 32
                                    + (size_t)(tl >> 3) * 2 + (tl & 1);
                    stq(r2h + fo, Hh); stq(r2l + fo, Hl);
                }
            }
            __syncthreads();   // each wave drains vmcnt -> all stores MALL-acked
            if (tid == 0 && s < TT)
                __hip_atomic_store(seq + w * SEQPAD, s + 1,
                                   __ATOMIC_RELAXED, __HIP_MEMORY_SCOPE_AGENT);
        }
        // save c-state for next chunk
        {
            const int ut = tid & 127;
            const int b = ut >> 3, j4v = (ut & 7) * 4;
            float* cs = (tid < 128) ? c0s : c1s;
            if (tid < 256) {
                f32x4 cv = {c4[0], c4[1], c4[2], c4[3]};
                *(f32x4*)(cs + (size_t)b * HH + w * 32 + j4v) = cv;
            }
        }
    } else {
        // ---------------- L1 compute (t1 = s-1) ----------------
        const int vv = v - 4;
        const int quad = vv >> 1, kh = vv & 1;
        const int qA = quad * 2, qB = quad * 2 + 1;
        const int r0 = qA * 256 + w * 32 + 0  + ln15;
        const int r1 = qA * 256 + w * 32 + 16 + ln15;
        const int r2 = qB * 256 + w * 32 + 0  + ln15;
        const int r3 = qB * 256 + w * 32 + 16 + ln15;

        bf16x8 I0k0,I0k1,I0k2,I0k3, I1k0,I1k1,I1k2,I1k3;
        bf16x8 I2k0,I2k1,I2k2,I2k3, I3k0,I3k1,I3k2,I3k3;
        bf16x8 H0k0,H0k1,H0k2,H0k3, H1k0,H1k1,H1k2,H1k3;
        bf16x8 H2k0,H2k1,H2k2,H2k3, H3k0,H3k1,H3k2,H3k3;
#define LW1(T, RT)                                                              \
        { const float* pi_ = Wih1 + (size_t)(RT) * HH + kh * 128 + kgrp * 8;    \
          LOADWH(I##T##k0, pi_);      LOADWH(I##T##k1, pi_ + 32);               \
          LOADWH(I##T##k2, pi_ + 64); LOADWH(I##T##k3, pi_ + 96);               \
          const float* ph_ = Whh1 + (size_t)(RT) * HH + kh * 128 + kgrp * 8;    \
          LOADWH(H##T##k0, ph_);      LOADWH(H##T##k1, ph_ + 32);               \
          LOADWH(H##T##k2, ph_ + 64); LOADWH(H##T##k3, ph_ + 96); }
        LW1(0, r0) LW1(1, r1) LW1(2, r2) LW1(3, r3)
#undef LW1
        const float bb0 = (kh == 0) ? b1v[r0] : 0.f;
        const float bb1 = (kh == 0) ? b1v[r1] : 0.f;
        const float bb2 = (kh == 0) ? b1v[r2] : 0.f;
        const float bb3 = (kh == 0) ? b1v[r3] : 0.f;

        for (int s = t0; s < tEnd; s++) {
            if (s >= 1) {
                f32x4 a0 = {bb0, bb0, bb0, bb0};
                f32x4 a1 = {bb1, bb1, bb1, bb1};
                f32x4 a2 = {bb2, bb2, bb2, bb2};
                f32x4 a3 = {bb3, bb3, bb3, bb3};
                pollwave(seq, s);
                const size_t lanep = (size_t)(kgrp * 16 + ln15) * 2;
                const size_t rb1 = (size_t)((s - 1) & (RINGN - 1)) * 1024 + lanep;
                U2 Ah0, Ah1, Ah2, Ah3, Al0, Al1, Al2, Al3;
#define RL1(k)                                                                  \
                { const size_t o = rb1 + (size_t)(kh * 4 + k) * 128;            \
                  Ah##k.u.a = ldq(r1h + o); Ah##k.u.b = ldq(r1h + o + 1);       \
                  Al##k.u.a = ldq(r1l + o); Al##k.u.b = ldq(r1l + o + 1); }
                RL1(0) RL1(1) RL1(2) RL1(3)
#undef RL1
                if (s >= 2) {
                    const size_t rb2 = (size_t)((s - 2) & (RINGN - 1)) * 1024 + lanep;
                    U2 Ch0, Ch1, Ch2, Ch3, Cl0, Cl1, Cl2, Cl3;
#define RL2(k)                                                                  \
                    { const size_t o = rb2 + (size_t)(kh * 4 + k) * 128;        \
                      Ch##k.u.a = ldq(r2h + o); Ch##k.u.b = ldq(r2h + o + 1);   \
                      Cl##k.u.a = ldq(r2l + o); Cl##k.u.b = ldq(r2l + o + 1); }
                    RL2(0) RL2(1) RL2(2) RL2(3)
#undef RL2
#define MK1(k)                                                                  \
                    MFA(a0, Ah##k.v, I0k##k); MFA(a0, Al##k.v, I0k##k);         \
                    MFA(a1, Ah##k.v, I1k##k); MFA(a1, Al##k.v, I1k##k);         \
                    MFA(a2, Ah##k.v, I2k##k); MFA(a2, Al##k.v, I2k##k);         \
                    MFA(a3, Ah##k.v, I3k##k); MFA(a3, Al##k.v, I3k##k);         \
                    MFA(a0, Ch##k.v, H0k##k); MFA(a0, Cl##k.v, H0k##k);         \
                    MFA(a1, Ch##k.v, H1k##k); MFA(a1, Cl##k.v, H1k##k);         \
                    MFA(a2, Ch##k.v, H2k##k); MFA(a2, Cl##k.v, H2k##k);         \
                    MFA(a3, Ch##k.v, H3k##k); MFA(a3, Cl##k.v, H3k##k);
                    MK1(0) MK1(1) MK1(2) MK1(3)
#undef MK1
                } else {
#define MK1B(k)                                                                 \
                    MFA(a0, Ah##k.v, I0k##k); MFA(a0, Al##k.v, I0k##k);         \
                    MFA(a1, Ah##k.v, I1k##k); MFA(a1, Al##k.v, I1k##k);         \
                    MFA(a2, Ah##k.v, I2k##k); MFA(a2, Al##k.v, I2k##k);         \
                    MFA(a3, Ah##k.v, I3k##k); MFA(a3, Al##k.v, I3k##k);
                    MK1B(0) MK1B(1) MK1B(2) MK1B(3)
#undef MK1B
                }
#pragma unroll
                for (int r = 0; r < 4; r++) {
                    gP[1][kh][qA][kgrp * 4 + r][0  + ln15] = a0[r];
                    gP[1][kh][qA][kgrp * 4 + r][16 + ln15] = a1[r];
                    gP[1][kh][qB][kgrp * 4 + r][0  + ln15] = a2[r];
                    gP[1][kh][qB][kgrp * 4 + r][16 + ln15] = a3[r];
                }
            }
            __syncthreads();
            // (update phase runs on waves 0-3)
            __syncthreads();
        }
    }
}

extern "C" void kernel_launch(void* const* d_in, const int* in_sizes, int n_in,
                              void* d_out, int out_size, void* d_ws, size_t ws_size,
                              hipStream_t stream) {
    (void)in_sizes; (void)n_in; (void)out_size;
    const float* x    = (const float*)d_in[0];
    const float* Wih0 = (const float*)d_in[1];
    const float* Whh0 = (const float*)d_in[2];
    const float* b0   = (const float*)d_in[3];
    const float* Wih1 = (const float*)d_in[4];
    const float* Whh1 = (const float*)d_in[5];
    const float* b1   = (const float*)d_in[6];
    float* out = (float*)d_out;

    // ---- workspace carve ----
    char* ws = (char*)d_ws;
    int*   seq = (int*)ws;                      // [8][SEQPAD]
    float* c0s = (float*)(seq + 8 * SEQPAD);    // [16][256]
    float* c1s = c0s + BQ * HH;
    u64t*  r1h = (u64t*)(c1s + BQ * HH);        // rings: [RINGN][1024] u64 each
    u64t*  r1l = r1h + RINGN * 1024;
    u64t*  r2h = r1l + RINGN * 1024;
    u64t*  r2l = r2h + RINGN * 1024;
    float* xw  = (float*)(r2l + RINGN * 1024);  // [TC][1024][16] f32
    const size_t fixedBytes = (size_t)((char*)xw - ws);

    int TC = TT;
    while (TC > 512 && fixedBytes + (size_t)TC * 1024 * BQ * 4 > ws_size) TC >>= 1;

    hipMemsetAsync(ws, 0, fixedBytes, stream);

    for (int t0 = 0; t0 < TT; t0 += TC) {
        xw_gemm<<<dim3((TC / 8) * 4), 256, 0, stream>>>(x, Wih0, b0, xw, t0, TC);
        const int tEnd = t0 + TC + ((t0 + TC == TT) ? 1 : 0);
        lstm_ring<<<8, 512, 0, stream>>>(Whh0, Wih1, Whh1, b1, xw,
                                         r1h, r1l, r2h, r2l,
                                         out, c0s, c1s, seq, t0, tEnd);
    }
}